// Round 7
// baseline (72.759 us; speedup 1.0000x reference)
//
#include <hip/hip_runtime.h>

// Problem constants (fixed by setup_inputs)
#define T_DIM 32
#define B_DIM 64
#define D_DIM 256
#define P_DIM 1024
#define NK    17
#define DT    0.1875f    // 3/16
#define DT_REV 0.029841551329651566f   // DT / (2*pi) -- v_sin/v_cos take revolutions

#define LROWA 264        // padded A^T row in bf16 (256+8)

typedef __bf16 bf16x8 __attribute__((ext_vector_type(8)));
typedef float  f32x16 __attribute__((ext_vector_type(16)));

static __device__ __forceinline__ unsigned f2bf(float f) {
  unsigned u = __float_as_uint(f);
  u += 0x7fffu + ((u >> 16) & 1u);     // round-to-nearest-even
  return u >> 16;
}

// Opaque zero derived from x: forces the wave to wait for x (s_waitcnt) and
// gives the compiler an unfoldable data dependency.
static __device__ __forceinline__ int dep_zero(float x) {
  int d;
  asm volatile("v_and_b32 %0, 0, %1" : "=v"(d) : "v"(x));
  return d;
}

// Module-scope scratch (load-time zero-init; NOT poisoned by the harness).
// ALL accesses are RELAXED device-scope atomics. No acquire/release (R4/R5
// lesson: each ordered agent-scope op costs L2 maintenance on non-coherent
// XCDs). FLAT structure (R6 lesson: dependent-hop trees serialize ~0.7 us
// cross-XCD round trips; independent relaxed adds pipeline at the L2
// service point).
//   g_sum: 64 accumulator lines (128 B apart) -- 8 blocks each, concurrent.
//   g_counter: single arrival counter; 512 relaxed same-line adds pipeline.
// Re-arm: finisher atomicExch's all 64 lines to 0 (one parallel round trip);
// counter never reset -- last-arrival test is (old & 511) == 511, wrap-safe.
__device__ float g_sum[64 * 32];
__device__ int   g_counter = 0;

// ---------------------------------------------------------------------------
// Single dispatch, no memset. grid (16 ptile, 32 t) x 256 thr (4 waves).
// Compute phase byte-identical to round-6 (passed, absmax 0.0):
//  - proj MFMA fragments global->register, fp32->bf16 in-register
//  - A staged once (full K=256) into LDS transposed [p][k] bf16; column
//    sq-norm partials accumulated during staging (norm applied after GEMM)
//  - 16 back-to-back 32x32x16 bf16 MFMAs, one 32x32 tile per wave
//  - HW trig (v_sin/v_cos, revolutions) + Chebyshev recurrence
// Tail (the only change vs R6): flat relaxed sum-add to g_sum[bid&63] +
// dep-forced relaxed counter add; the 512th arrival's wave-0 does 64
// parallel atomicExch (gather + re-arm in one RMW each), shfl-reduces,
// plain-stores out[0] over the poison.
//
// LDS: planes ALIAS the dead A^T tile (all sa ds_reads drain before barrier
// (2); planes written after) -> 38160 B/block -> 4 blocks/CU.
//   sa [64][264] bf16 @0 (33792 B) | normred @8448 | invn @9472 | parts @9536
//   planes: cos[16][128] @0, sin @2048  (alias sa)
// ---------------------------------------------------------------------------
__global__ __launch_bounds__(256) void sig_fused_kernel(const float* __restrict__ proj,
                                                        const float* __restrict__ A,
                                                        float* __restrict__ out) {
  __shared__ float smf[9540];
  unsigned short* sa = (unsigned short*)smf;     // A^T tile [p][k], padded
  float* normred = smf + 8448;                   // [16 kg][64 p]
  float* invn    = smf + 9472;                   // [64]
  float* planes  = smf;                          // aliases sa (safe post-(2))
  float* parts   = smf + 9536;                   // [4]

  const int tid  = threadIdx.x;
  const int lane = tid & 63;
  const int wv   = tid >> 6;                     // 0..3
  const int p0   = blockIdx.x * 64;
  const int t    = blockIdx.y;

  const int mt  = wv >> 1, nt = wv & 1;
  const int l31 = lane & 31;
  const int hi  = lane >> 5;                     // k-sub half

  // ---- proj fragments: direct global->reg, convert to bf16 ----
  const float* Pr = proj + ((size_t)t * B_DIM + mt * 32 + l31) * D_DIM + hi * 8;
  bf16x8 af[16];
#pragma unroll
  for (int ks = 0; ks < 16; ++ks) {
    float4 u0 = *(const float4*)(Pr + ks * 16);
    float4 u1 = *(const float4*)(Pr + ks * 16 + 4);
    union { bf16x8 v; unsigned u[4]; } w;
    w.u[0] = f2bf(u0.x) | (f2bf(u0.y) << 16);
    w.u[1] = f2bf(u0.z) | (f2bf(u0.w) << 16);
    w.u[2] = f2bf(u1.x) | (f2bf(u1.y) << 16);
    w.u[3] = f2bf(u1.z) | (f2bf(u1.w) << 16);
    af[ks] = w.v;
  }

  // ---- A-stage: full K, transpose + convert + norm partials ----
  {
    const int pg = tid & 15;                     // p-group (4 p's)
    const int kg = tid >> 4;                     // 0..15, 16 k's each
    const float4* Ag = (const float4*)(A + p0); // row stride P_DIM/4 float4
    float4 va[16];
#pragma unroll
    for (int i = 0; i < 16; ++i)
      va[i] = Ag[(size_t)(kg * 16 + i) * (P_DIM / 4) + pg];
    float nrm[4] = {0.f, 0.f, 0.f, 0.f};
#pragma unroll
    for (int j = 0; j < 4; ++j) {
#pragma unroll
      for (int h = 0; h < 2; ++h) {
        float e0 = ((const float*)&va[h * 8 + 0])[j];
        float e1 = ((const float*)&va[h * 8 + 1])[j];
        float e2 = ((const float*)&va[h * 8 + 2])[j];
        float e3 = ((const float*)&va[h * 8 + 3])[j];
        float e4 = ((const float*)&va[h * 8 + 4])[j];
        float e5 = ((const float*)&va[h * 8 + 5])[j];
        float e6 = ((const float*)&va[h * 8 + 6])[j];
        float e7 = ((const float*)&va[h * 8 + 7])[j];
        nrm[j] = fmaf(e0, e0, nrm[j]); nrm[j] = fmaf(e1, e1, nrm[j]);
        nrm[j] = fmaf(e2, e2, nrm[j]); nrm[j] = fmaf(e3, e3, nrm[j]);
        nrm[j] = fmaf(e4, e4, nrm[j]); nrm[j] = fmaf(e5, e5, nrm[j]);
        nrm[j] = fmaf(e6, e6, nrm[j]); nrm[j] = fmaf(e7, e7, nrm[j]);
        uint4 w;
        w.x = f2bf(e0) | (f2bf(e1) << 16);
        w.y = f2bf(e2) | (f2bf(e3) << 16);
        w.z = f2bf(e4) | (f2bf(e5) << 16);
        w.w = f2bf(e6) | (f2bf(e7) << 16);
        *(uint4*)&sa[(pg * 4 + j) * LROWA + kg * 16 + h * 8] = w;
      }
      normred[kg * 64 + pg * 4 + j] = nrm[j];
    }
  }
  __syncthreads();                               // (1) A tile + normred ready

  // ---- finish column norms -> invn[p] (overlaps other waves' MFMA) ----
  if (tid < 64) {
    float s = 0.f;
#pragma unroll
    for (int q = 0; q < 16; ++q) s += normred[q * 64 + tid];
    invn[tid] = rsqrtf(fmaxf(s, 1e-24f));        // 1/clamp_min(norm, 1e-12)
  }

  // ---- MFMA: 16 k-steps over full K ----
  f32x16 acc = {0.f, 0.f, 0.f, 0.f, 0.f, 0.f, 0.f, 0.f,
                0.f, 0.f, 0.f, 0.f, 0.f, 0.f, 0.f, 0.f};
  const unsigned short* brow = &sa[(nt * 32 + l31) * LROWA + hi * 8];
#pragma unroll
  for (int ks = 0; ks < 16; ++ks) {
    bf16x8 bfr = *(const bf16x8*)(brow + ks * 16);
    acc = __builtin_amdgcn_mfma_f32_32x32x16_bf16(af[ks], bfr, acc, 0, 0, 0);
  }
  // acc reg r = x_unnorm[b = mt*32+(r&3)+8*(r>>2)+4*hi][p = nt*32+l31]
  __syncthreads();                               // (2) invn ready; sa dead

  // scale to REVOLUTIONS: theta = x*DT, hw trig wants theta/2pi
  const float invdt = invn[nt * 32 + l31] * DT_REV;

  // ---- Chebyshev trig via HW v_sin/v_cos: sums over this lane's 16 b's ----
  float cs[NK - 1], ss[NK - 1];
#pragma unroll
  for (int k = 0; k < NK - 1; ++k) { cs[k] = 0.f; ss[k] = 0.f; }
#pragma unroll
  for (int r = 0; r < 16; ++r) {
    float th = acc[r] * invdt;                   // revolutions, |th| << 1
    float c1 = __builtin_amdgcn_cosf(th);        // v_cos_f32: cos(2*pi*th)
    float s1 = __builtin_amdgcn_sinf(th);        // v_sin_f32: sin(2*pi*th)
    float twoc = 2.f * c1;
    float ckm1 = 1.f, skm1 = 0.f;
    float ck = c1, sk = s1;
    cs[0] += c1;
    ss[0] += s1;
#pragma unroll
    for (int k = 2; k < NK; ++k) {
      float cn = fmaf(twoc, ck, -ckm1);
      float sn = fmaf(twoc, sk, -skm1);
      cs[k - 1] += cn;
      ss[k - 1] += sn;
      ckm1 = ck; skm1 = sk; ck = cn; sk = sn;
    }
  }

  // ---- combine the two b-halves (lane L and L^32 share the same p col) ----
#pragma unroll
  for (int k = 0; k < NK - 1; ++k) {
    cs[k] += __shfl_xor(cs[k], 32, 64);
    ss[k] += __shfl_xor(ss[k], 32, 64);
  }

  // ---- planes (alias dead sa): cos[16][2 mt][64 p], sin @ +2048 ----
  if (lane < 32) {
    int p = nt * 32 + l31;
#pragma unroll
    for (int k = 0; k < NK - 1; ++k) {
      planes[k * 128 + mt * 64 + p]        = cs[k];
      planes[2048 + k * 128 + mt * 64 + p] = ss[k];
    }
  }
  __syncthreads();                               // (3) planes ready

  // ---- per-(k,p) error + weight dot ----
  float part = 0.f;
#pragma unroll
  for (int r = 0; r < 4; ++r) {
    int e  = tid + r * 256;                      // 0..1023
    int k1 = e >> 6;
    int pl = e & 63;
    float C = planes[k1 * 128 + pl] + planes[k1 * 128 + 64 + pl];
    float S = planes[2048 + k1 * 128 + pl] + planes[2048 + k1 * 128 + 64 + pl];
    float cm  = C * (1.f / 64.f);
    float sm_ = S * (1.f / 64.f);
    float tk  = (float)(k1 + 1) * DT;
    float phi = __expf(-0.5f * tk * tk);
    float wk  = ((k1 == NK - 2) ? DT : 2.f * DT) * phi;   // k=16 endpoint
    float dc  = cm - phi;
    part = fmaf(wk, fmaf(dc, dc, sm_ * sm_), part);
  }
  part *= (1.f / 512.f);                         // * B / (T*P)

  // ---- block reduce ----
#pragma unroll
  for (int off = 32; off > 0; off >>= 1)
    part += __shfl_down(part, off, 64);
  if (lane == 0) parts[wv] = part;
  __syncthreads();                               // (4) partials ready

  // ---- flat relaxed tail: spread sum lines + single counter ----
  if (wv == 0) {
    const int bid = t * 16 + blockIdx.x;         // 0..511; bid&63 spreads
    int isl = 0;
    if (lane == 0) {
      float total = parts[0] + parts[1] + parts[2] + parts[3];
      float oldv = atomicAdd(&g_sum[(bid & 63) * 32], total);
      // dep_zero: sum-RMW provably performed before the counter bump issues
      int oc = atomicAdd(&g_counter, 1 + dep_zero(oldv));
      isl = ((oc & 511) == 511);                 // wrap-safe across replays
    }
    isl = __shfl(isl, 0, 64);
    if (isl) {
      // All 512 sum-RMWs performed (counter protocol). 64 parallel
      // exchanges gather + re-arm each line in one round trip.
      float s = atomicExch(&g_sum[lane * 32], 0.0f);
#pragma unroll
      for (int off = 32; off > 0; off >>= 1)
        s += __shfl_down(s, off, 64);
      if (lane == 0) out[0] = s;                 // overwrite poison
    }
  }
}

// ---------------------------------------------------------------------------
extern "C" void kernel_launch(void* const* d_in, const int* in_sizes, int n_in,
                              void* d_out, int out_size, void* d_ws, size_t ws_size,
                              hipStream_t stream) {
  const float* proj = (const float*)d_in[0];     // (32,64,256) fp32
  const float* A    = (const float*)d_in[1];     // (256,1024) fp32
  float* out        = (float*)d_out;             // 1 fp32 scalar

  // ONE dispatch: no memset -- the finishing block plain-stores the scalar.
  sig_fused_kernel<<<dim3(16, 32), dim3(256), 0, stream>>>(proj, A, out);
}

// Round 8
// 69.400 us; speedup vs baseline: 1.0484x; 1.0484x over previous
//
#include <hip/hip_runtime.h>

// Problem constants (fixed by setup_inputs)
#define T_DIM 32
#define B_DIM 64
#define D_DIM 256
#define P_DIM 1024
#define NK    17
#define DT    0.1875f    // 3/16
#define DT_REV 0.029841551329651566f   // DT / (2*pi) -- v_sin/v_cos take revolutions

#define LROWA 264        // padded A^T row in bf16 (256+8)

typedef __bf16 bf16x8 __attribute__((ext_vector_type(8)));
typedef float  f32x16 __attribute__((ext_vector_type(16)));

// Native bf16 pack: gfx950 lowers fptrunc f32->bf16 to v_cvt_pk_bf16_f32
// (RNE) -- same bits as the old integer round-to-nearest-even for finite
// inputs, ~3x fewer VALU ops.
static __device__ __forceinline__ unsigned pkbf(float lo, float hi) {
  unsigned short a = __builtin_bit_cast(unsigned short, (__bf16)lo);
  unsigned short b = __builtin_bit_cast(unsigned short, (__bf16)hi);
  return (unsigned)a | ((unsigned)b << 16);
}

// Opaque zero derived from x: forces the wave to wait for x (s_waitcnt) and
// gives the compiler an unfoldable data dependency.
static __device__ __forceinline__ int dep_zero(float x) {
  int d;
  asm volatile("v_and_b32 %0, 0, %1" : "=v"(d) : "v"(x));
  return d;
}

// Module-scope scratch (load-time zero-init; NOT poisoned by the harness).
// ALL accesses RELAXED device-scope atomics (R4/R5 lesson: ordered
// agent-scope ops cost L2 maintenance on non-coherent XCDs). Flat structure
// (R6/R7: equal perf to trees; keep the simplest proven one).
__device__ float g_sum[64 * 32];
__device__ int   g_counter = 0;

// ---------------------------------------------------------------------------
// Single dispatch, no memset. grid (16 ptile, 32 t) x 256 thr (4 waves).
// vs R7 (passed, absmax 0.0) -- compute slimmed, structure identical:
//  - proj MFMA fragments global->register, fp32->bf16 via native casts
//  - A staged once (full K=256) into LDS transposed [p][k] bf16 (native
//    casts); fp32 column sq-norm partials during staging (norm after GEMM)
//  - 16 back-to-back 32x32x16 bf16 MFMAs, one 32x32 tile per wave
//  - HW trig (v_sin/v_cos, revolutions) + Chebyshev recurrence (unchanged)
//  - NEW epilogue: mt=1 waves write cs/ss (32 floats/lane, +1-padded rows,
//    conflict-free) into an exchange region aliasing the dead A-tile;
//    mt=0 waves combine in-register and evaluate all 16 harmonics' error
//    terms locally (no cos/sin planes, no plane re-reads).
//  - tail: R7's flat relaxed atomics, verbatim.
// LDS (floats): sa 0..8447 (33792 B) | normred @8448 | invn @9472 |
//   parts @9536 | exch ALIASES sa (written post-barrier (2), sa dead).
//   38160 B/block -> 4 blocks/CU.
// ---------------------------------------------------------------------------
__global__ __launch_bounds__(256) void sig_fused_kernel(const float* __restrict__ proj,
                                                        const float* __restrict__ A,
                                                        float* __restrict__ out) {
  __shared__ float smf[9540];
  unsigned short* sa = (unsigned short*)smf;     // A^T tile [p][k], padded
  float* normred = smf + 8448;                   // [16 kg][64 p]
  float* invn    = smf + 9472;                   // [64]
  float* exch    = smf;                          // aliases sa (safe post-(2))
  float* parts   = smf + 9536;                   // [2] used

  const int tid  = threadIdx.x;
  const int lane = tid & 63;
  const int wv   = tid >> 6;                     // 0..3
  const int p0   = blockIdx.x * 64;
  const int t    = blockIdx.y;

  const int mt  = wv >> 1, nt = wv & 1;
  const int l31 = lane & 31;
  const int hi  = lane >> 5;                     // k-sub half

  // ---- proj fragments: direct global->reg, convert to bf16 ----
  const float* Pr = proj + ((size_t)t * B_DIM + mt * 32 + l31) * D_DIM + hi * 8;
  bf16x8 af[16];
#pragma unroll
  for (int ks = 0; ks < 16; ++ks) {
    float4 u0 = *(const float4*)(Pr + ks * 16);
    float4 u1 = *(const float4*)(Pr + ks * 16 + 4);
    union { bf16x8 v; unsigned u[4]; } w;
    w.u[0] = pkbf(u0.x, u0.y);
    w.u[1] = pkbf(u0.z, u0.w);
    w.u[2] = pkbf(u1.x, u1.y);
    w.u[3] = pkbf(u1.z, u1.w);
    af[ks] = w.v;
  }

  // ---- A-stage: full K, transpose + convert + norm partials ----
  {
    const int pg = tid & 15;                     // p-group (4 p's)
    const int kg = tid >> 4;                     // 0..15, 16 k's each
    const float4* Ag = (const float4*)(A + p0); // row stride P_DIM/4 float4
    float4 va[16];
#pragma unroll
    for (int i = 0; i < 16; ++i)
      va[i] = Ag[(size_t)(kg * 16 + i) * (P_DIM / 4) + pg];
    float nrm[4] = {0.f, 0.f, 0.f, 0.f};
#pragma unroll
    for (int j = 0; j < 4; ++j) {
#pragma unroll
      for (int h = 0; h < 2; ++h) {
        float e0 = ((const float*)&va[h * 8 + 0])[j];
        float e1 = ((const float*)&va[h * 8 + 1])[j];
        float e2 = ((const float*)&va[h * 8 + 2])[j];
        float e3 = ((const float*)&va[h * 8 + 3])[j];
        float e4 = ((const float*)&va[h * 8 + 4])[j];
        float e5 = ((const float*)&va[h * 8 + 5])[j];
        float e6 = ((const float*)&va[h * 8 + 6])[j];
        float e7 = ((const float*)&va[h * 8 + 7])[j];
        nrm[j] = fmaf(e0, e0, nrm[j]); nrm[j] = fmaf(e1, e1, nrm[j]);
        nrm[j] = fmaf(e2, e2, nrm[j]); nrm[j] = fmaf(e3, e3, nrm[j]);
        nrm[j] = fmaf(e4, e4, nrm[j]); nrm[j] = fmaf(e5, e5, nrm[j]);
        nrm[j] = fmaf(e6, e6, nrm[j]); nrm[j] = fmaf(e7, e7, nrm[j]);
        uint4 w;
        w.x = pkbf(e0, e1);
        w.y = pkbf(e2, e3);
        w.z = pkbf(e4, e5);
        w.w = pkbf(e6, e7);
        *(uint4*)&sa[(pg * 4 + j) * LROWA + kg * 16 + h * 8] = w;
      }
      normred[kg * 64 + pg * 4 + j] = nrm[j];
    }
  }
  __syncthreads();                               // (1) A tile + normred ready

  // ---- finish column norms -> invn[p] (overlaps other waves' MFMA) ----
  if (tid < 64) {
    float s = 0.f;
#pragma unroll
    for (int q = 0; q < 16; ++q) s += normred[q * 64 + tid];
    invn[tid] = rsqrtf(fmaxf(s, 1e-24f));        // 1/clamp_min(norm, 1e-12)
  }

  // ---- MFMA: 16 k-steps over full K ----
  f32x16 acc = {0.f, 0.f, 0.f, 0.f, 0.f, 0.f, 0.f, 0.f,
                0.f, 0.f, 0.f, 0.f, 0.f, 0.f, 0.f, 0.f};
  const unsigned short* brow = &sa[(nt * 32 + l31) * LROWA + hi * 8];
#pragma unroll
  for (int ks = 0; ks < 16; ++ks) {
    bf16x8 bfr = *(const bf16x8*)(brow + ks * 16);
    acc = __builtin_amdgcn_mfma_f32_32x32x16_bf16(af[ks], bfr, acc, 0, 0, 0);
  }
  // acc reg r = x_unnorm[b = mt*32+(r&3)+8*(r>>2)+4*hi][p = nt*32+l31]
  __syncthreads();                               // (2) invn ready; sa dead

  // scale to REVOLUTIONS: theta = x*DT, hw trig wants theta/2pi
  const float invdt = invn[nt * 32 + l31] * DT_REV;

  // ---- Chebyshev trig via HW v_sin/v_cos: sums over this lane's 16 b's ----
  float cs[NK - 1], ss[NK - 1];
#pragma unroll
  for (int k = 0; k < NK - 1; ++k) { cs[k] = 0.f; ss[k] = 0.f; }
#pragma unroll
  for (int r = 0; r < 16; ++r) {
    float th = acc[r] * invdt;                   // revolutions, |th| << 1
    float c1 = __builtin_amdgcn_cosf(th);        // v_cos_f32: cos(2*pi*th)
    float s1 = __builtin_amdgcn_sinf(th);        // v_sin_f32: sin(2*pi*th)
    float twoc = 2.f * c1;
    float ckm1 = 1.f, skm1 = 0.f;
    float ck = c1, sk = s1;
    cs[0] += c1;
    ss[0] += s1;
#pragma unroll
    for (int k = 2; k < NK; ++k) {
      float cn = fmaf(twoc, ck, -ckm1);
      float sn = fmaf(twoc, sk, -skm1);
      cs[k - 1] += cn;
      ss[k - 1] += sn;
      ckm1 = ck; skm1 = sk; ck = cn; sk = sn;
    }
  }

  // ---- combine the two b-halves (lane L and L^32 share the same p col) ----
#pragma unroll
  for (int k = 0; k < NK - 1; ++k) {
    cs[k] += __shfl_xor(cs[k], 32, 64);
    ss[k] += __shfl_xor(ss[k], 32, 64);
  }

  // ---- mt=1 waves export cs/ss to exchange region (aliases dead sa) ----
  // row = nt*32 + l31, 33-float pad -> bank (l31+k)%32: conflict-free.
  if (mt == 1) {
    if (lane < 32) {
      float* row = &exch[(nt * 32 + l31) * 33];
#pragma unroll
      for (int k = 0; k < NK - 1; ++k) {
        row[k]      = cs[k];
        row[16 + k] = ss[k];
      }
    }
  }
  __syncthreads();                               // (3) exch ready

  // ---- mt=0 waves: combine + all-16-harmonics error in-register ----
  if (mt == 0) {
    const float* row = &exch[(nt * 32 + l31) * 33];
    float part = 0.f;
#pragma unroll
    for (int k = 0; k < NK - 1; ++k) {
      float C = cs[k] + row[k];
      float S = ss[k] + row[16 + k];
      float cm  = C * (1.f / 64.f);
      float sm_ = S * (1.f / 64.f);
      float tk  = (float)(k + 1) * DT;
      float phi = __expf(-0.5f * tk * tk);
      float wk  = ((k == NK - 2) ? DT : 2.f * DT) * phi;  // k=16 endpoint
      float dc  = cm - phi;
      part = fmaf(wk, fmaf(dc, dc, sm_ * sm_), part);
    }
    // lanes L and L^32 hold identical values -> wave sum double-counts 2x:
    // scale = B/(T*P) / 2 = (1/512)/2
    part *= (1.f / 1024.f);
#pragma unroll
    for (int off = 32; off > 0; off >>= 1)
      part += __shfl_down(part, off, 64);
    if (lane == 0) parts[nt] = part;
  }
  __syncthreads();                               // (4) parts ready

  // ---- flat relaxed tail (verbatim R7): spread sum lines + one counter ----
  if (wv == 0) {
    const int bid = t * 16 + blockIdx.x;         // 0..511; bid&63 spreads
    int isl = 0;
    if (lane == 0) {
      float total = parts[0] + parts[1];
      float oldv = atomicAdd(&g_sum[(bid & 63) * 32], total);
      // dep_zero: sum-RMW provably performed before the counter bump issues
      int oc = atomicAdd(&g_counter, 1 + dep_zero(oldv));
      isl = ((oc & 511) == 511);                 // wrap-safe across replays
    }
    isl = __shfl(isl, 0, 64);
    if (isl) {
      // All 512 sum-RMWs performed (counter protocol). 64 parallel
      // exchanges gather + re-arm each line in one round trip.
      float s = atomicExch(&g_sum[lane * 32], 0.0f);
#pragma unroll
      for (int off = 32; off > 0; off >>= 1)
        s += __shfl_down(s, off, 64);
      if (lane == 0) out[0] = s;                 // overwrite poison
    }
  }
}

// ---------------------------------------------------------------------------
extern "C" void kernel_launch(void* const* d_in, const int* in_sizes, int n_in,
                              void* d_out, int out_size, void* d_ws, size_t ws_size,
                              hipStream_t stream) {
  const float* proj = (const float*)d_in[0];     // (32,64,256) fp32
  const float* A    = (const float*)d_in[1];     // (256,1024) fp32
  float* out        = (float*)d_out;             // 1 fp32 scalar

  // ONE dispatch: no memset -- the finishing block plain-stores the scalar.
  sig_fused_kernel<<<dim3(16, 32), dim3(256), 0, stream>>>(proj, A, out);
}